// Round 1
// baseline (161.996 us; speedup 1.0000x reference)
//
#include <hip/hip_runtime.h>
#include <hip/hip_bf16.h>
#include <math.h>

#define B_   256
#define IN_  512
#define OUT_ 512
#define E_   256
#define DELTA_ 0.1f
#define LN_EPS_ 1e-5f

// ---------------------------------------------------------------------------
// K1: scores = pred_emb @ attn_w^T + attn_b  (rows i), row-LayerNorm, sigmoid,
//     then write wv[i][o] = (W[o][i], |W[o][i]| * sig[i][o])  (interleaved,
//     transposed so K2 reads are coalesced 8B loads).
// Block: 256 threads, handles ROWS=4 consecutive i-rows, all 512 o.
// Grid: IN/ROWS = 128 blocks.
// ---------------------------------------------------------------------------
#define K1_ROWS 4

__global__ __launch_bounds__(256)
void k1_scores_ln_sig(const float* __restrict__ pred_emb,
                      const float* __restrict__ attn_w,
                      const float* __restrict__ attn_b,
                      const float* __restrict__ ln_g,
                      const float* __restrict__ ln_b,
                      const float* __restrict__ weights,
                      float2* __restrict__ wv) {
    __shared__ float pe[K1_ROWS][E_];          // 4 KB
    __shared__ float red[4][K1_ROWS][2];       // [wave][row][{sum,sumsq}]
    __shared__ float smu[K1_ROWS], srs[K1_ROWS];

    const int t    = threadIdx.x;              // 0..255
    const int lane = t & 63;
    const int wid  = t >> 6;
    const int i0   = blockIdx.x * K1_ROWS;

    // stage pred_emb rows (E_ == 256 == blockDim)
    #pragma unroll
    for (int r = 0; r < K1_ROWS; ++r)
        pe[r][t] = pred_emb[(size_t)(i0 + r) * E_ + t];
    __syncthreads();

    const float4 (*pe4)[E_ / 4] = reinterpret_cast<const float4(*)[E_ / 4]>(pe);

    // each thread: o = t and o = t+256, dot over E for each of 4 rows
    float acc[K1_ROWS][2];
    #pragma unroll
    for (int oo = 0; oo < 2; ++oo) {
        const int o = t + oo * 256;
        const float4* wrow = reinterpret_cast<const float4*>(attn_w + (size_t)o * E_);
        float a0 = 0.f, a1 = 0.f, a2 = 0.f, a3 = 0.f;
        #pragma unroll 8
        for (int e4 = 0; e4 < E_ / 4; ++e4) {
            float4 w4 = wrow[e4];
            float4 p0 = pe4[0][e4];
            float4 p1 = pe4[1][e4];
            float4 p2 = pe4[2][e4];
            float4 p3 = pe4[3][e4];
            a0 += p0.x * w4.x + p0.y * w4.y + p0.z * w4.z + p0.w * w4.w;
            a1 += p1.x * w4.x + p1.y * w4.y + p1.z * w4.z + p1.w * w4.w;
            a2 += p2.x * w4.x + p2.y * w4.y + p2.z * w4.z + p2.w * w4.w;
            a3 += p3.x * w4.x + p3.y * w4.y + p3.z * w4.z + p3.w * w4.w;
        }
        const float bo = attn_b[o];
        acc[0][oo] = a0 + bo;
        acc[1][oo] = a1 + bo;
        acc[2][oo] = a2 + bo;
        acc[3][oo] = a3 + bo;
    }

    // block reductions for per-row mean / var over 512 o-values
    #pragma unroll
    for (int r = 0; r < K1_ROWS; ++r) {
        float s1 = acc[r][0] + acc[r][1];
        float s2 = acc[r][0] * acc[r][0] + acc[r][1] * acc[r][1];
        #pragma unroll
        for (int off = 32; off > 0; off >>= 1) {
            s1 += __shfl_down(s1, off);
            s2 += __shfl_down(s2, off);
        }
        if (lane == 0) { red[wid][r][0] = s1; red[wid][r][1] = s2; }
    }
    __syncthreads();
    if (t < K1_ROWS) {
        float s1 = red[0][t][0] + red[1][t][0] + red[2][t][0] + red[3][t][0];
        float s2 = red[0][t][1] + red[1][t][1] + red[2][t][1] + red[3][t][1];
        float mu  = s1 / (float)OUT_;
        float var = s2 / (float)OUT_ - mu * mu;
        smu[t] = mu;
        srs[t] = rsqrtf(var + LN_EPS_);
    }
    __syncthreads();

    // LN + sigmoid + fused operand write
    #pragma unroll
    for (int oo = 0; oo < 2; ++oo) {
        const int o = t + oo * 256;
        const float g  = ln_g[o];
        const float bb = ln_b[o];
        #pragma unroll
        for (int r = 0; r < K1_ROWS; ++r) {
            float z  = (acc[r][oo] - smu[r]) * srs[r] * g + bb;
            float sg = 1.f / (1.f + expf(-z));
            float w  = weights[(size_t)o * IN_ + (i0 + r)];
            wv[(size_t)(i0 + r) * OUT_ + o] = make_float2(w, fabsf(w) * sg);
        }
    }
}

// ---------------------------------------------------------------------------
// K2: out[b,o] = dot(x[b,:], W[o,:]) + DELTA*(max_i u*v - sum_i u*v)
//     with u = x*|x| staged in LDS, wv = (W^T, v) read coalesced.
// Block: 256 threads = 16 o-lanes x 16 b-lanes; tile 32 b x 16 o.
// Grid: (OUT/16, B/32) = (32, 8) = 256 blocks.
// i-loop chunked by 128 through LDS (row stride padded +4 floats -> no
// 4-way bank conflict on the 512B-stride reads).
// ---------------------------------------------------------------------------
#define K2_BT 32
#define K2_OT 16
#define K2_CH 128
#define K2_PAD 4
#define K2_STRIDE4 ((K2_CH + K2_PAD) / 4)   // 33 float4 per row

__global__ __launch_bounds__(256)
void k2_main(const float* __restrict__ x,
             const float2* __restrict__ wv,
             float* __restrict__ out) {
    __shared__ float4 xs4[K2_BT * K2_STRIDE4];   // 16.5 KB
    __shared__ float4 us4[K2_BT * K2_STRIDE4];   // 16.5 KB

    const int t  = threadIdx.x;
    const int ot = t & 15;            // o lane
    const int bl = t >> 4;            // 0..15
    const int o0 = blockIdx.x * K2_OT;
    const int b0 = blockIdx.y * K2_BT;
    const int o  = o0 + ot;

    float da = 0.f, sa = 0.f, ma = -INFINITY;
    float db = 0.f, sb = 0.f, mb = -INFINITY;

    for (int c = 0; c < IN_ / K2_CH; ++c) {
        __syncthreads();   // previous chunk's reads done before overwrite
        // stage x tile (32 rows x 128 cols) + u = x*|x|
        #pragma unroll
        for (int k = 0; k < 4; ++k) {
            int p    = t + k * 256;        // 0..1023
            int row  = p >> 5;             // /32
            int col4 = p & 31;
            float4 xv = reinterpret_cast<const float4*>(
                x + (size_t)(b0 + row) * IN_ + c * K2_CH)[col4];
            float4 uv = make_float4(xv.x * fabsf(xv.x), xv.y * fabsf(xv.y),
                                    xv.z * fabsf(xv.z), xv.w * fabsf(xv.w));
            xs4[row * K2_STRIDE4 + col4] = xv;
            us4[row * K2_STRIDE4 + col4] = uv;
        }
        __syncthreads();

        const float2* wbase = wv + (size_t)(c * K2_CH) * OUT_ + o;
        #pragma unroll 8
        for (int i4 = 0; i4 < K2_CH / 4; ++i4) {
            float4 xa = xs4[bl * K2_STRIDE4 + i4];
            float4 ua = us4[bl * K2_STRIDE4 + i4];
            float4 xb = xs4[(bl + 16) * K2_STRIDE4 + i4];
            float4 ub = us4[(bl + 16) * K2_STRIDE4 + i4];
            const float2* wp = wbase + (size_t)(i4 * 4) * OUT_;
            float2 w0 = wp[0];
            float2 w1 = wp[OUT_];
            float2 w2 = wp[2 * OUT_];
            float2 w3 = wp[3 * OUT_];
            float p;
            da = fmaf(xa.x, w0.x, da); p = ua.x * w0.y; sa += p; ma = fmaxf(ma, p);
            db = fmaf(xb.x, w0.x, db); p = ub.x * w0.y; sb += p; mb = fmaxf(mb, p);
            da = fmaf(xa.y, w1.x, da); p = ua.y * w1.y; sa += p; ma = fmaxf(ma, p);
            db = fmaf(xb.y, w1.x, db); p = ub.y * w1.y; sb += p; mb = fmaxf(mb, p);
            da = fmaf(xa.z, w2.x, da); p = ua.z * w2.y; sa += p; ma = fmaxf(ma, p);
            db = fmaf(xb.z, w2.x, db); p = ub.z * w2.y; sb += p; mb = fmaxf(mb, p);
            da = fmaf(xa.w, w3.x, da); p = ua.w * w3.y; sa += p; ma = fmaxf(ma, p);
            db = fmaf(xb.w, w3.x, db); p = ub.w * w3.y; sb += p; mb = fmaxf(mb, p);
        }
    }

    out[(size_t)(b0 + bl) * OUT_ + o]        = da + DELTA_ * (ma - sa);
    out[(size_t)(b0 + bl + 16) * OUT_ + o]   = db + DELTA_ * (mb - sb);
}

// ---------------------------------------------------------------------------
extern "C" void kernel_launch(void* const* d_in, const int* in_sizes, int n_in,
                              void* d_out, int out_size, void* d_ws, size_t ws_size,
                              hipStream_t stream) {
    const float* x        = (const float*)d_in[0];
    const float* weights  = (const float*)d_in[1];
    const float* pred_emb = (const float*)d_in[2];
    const float* attn_w   = (const float*)d_in[3];
    const float* attn_b   = (const float*)d_in[4];
    const float* ln_g     = (const float*)d_in[5];
    const float* ln_b     = (const float*)d_in[6];
    float* out = (float*)d_out;

    float2* wv = (float2*)d_ws;   // IN_*OUT_ float2 = 2 MB scratch

    k1_scores_ln_sig<<<IN_ / K1_ROWS, 256, 0, stream>>>(
        pred_emb, attn_w, attn_b, ln_g, ln_b, weights, wv);

    k2_main<<<dim3(OUT_ / K2_OT, B_ / K2_BT), 256, 0, stream>>>(x, wv, out);
}

// Round 2
// 101.427 us; speedup vs baseline: 1.5972x; 1.5972x over previous
//
#include <hip/hip_runtime.h>
#include <hip/hip_bf16.h>
#include <math.h>

#define B_   256
#define IN_  512
#define OUT_ 512
#define E_   256
#define DELTA_ 0.1f
#define LN_EPS_ 1e-5f

// ---------------------------------------------------------------------------
// K1: scores = pred_emb @ attn_w^T + attn_b (rows i), row-LN, sigmoid,
//     wv[i][o] = (W[o][i], |W[o][i]|*sig[i][o]).
// 2 rows per block -> 256 blocks (1/CU, all CUs busy), 256 threads.
// attn_w streamed float4 with deep unroll (8 loads in flight covers L2 lat).
// ---------------------------------------------------------------------------
#define K1_R 2

__global__ __launch_bounds__(256)
void k1_scores_ln_sig(const float* __restrict__ pred_emb,
                      const float* __restrict__ attn_w,
                      const float* __restrict__ attn_b,
                      const float* __restrict__ ln_g,
                      const float* __restrict__ ln_b,
                      const float* __restrict__ weights,
                      float2* __restrict__ wv) {
    __shared__ float pe[K1_R][E_];
    __shared__ float red[4][K1_R][2];
    __shared__ float smu[K1_R], srs[K1_R];

    const int t    = threadIdx.x;
    const int lane = t & 63;
    const int wid  = t >> 6;
    const int i0   = blockIdx.x * K1_R;

    #pragma unroll
    for (int r = 0; r < K1_R; ++r)
        pe[r][t] = pred_emb[(size_t)(i0 + r) * E_ + t];
    __syncthreads();

    const float4 (*pe4)[E_ / 4] = reinterpret_cast<const float4(*)[E_ / 4]>(pe);

    float acc[K1_R][2];
    #pragma unroll
    for (int oo = 0; oo < 2; ++oo) {
        const int o = t + oo * 256;
        const float4* wrow = reinterpret_cast<const float4*>(attn_w + (size_t)o * E_);
        float a0 = 0.f, a1 = 0.f;
        #pragma unroll 8
        for (int e4 = 0; e4 < E_ / 4; ++e4) {
            float4 w4 = wrow[e4];
            float4 p0 = pe4[0][e4];
            float4 p1 = pe4[1][e4];
            a0 += p0.x * w4.x + p0.y * w4.y + p0.z * w4.z + p0.w * w4.w;
            a1 += p1.x * w4.x + p1.y * w4.y + p1.z * w4.z + p1.w * w4.w;
        }
        const float bo = attn_b[o];
        acc[0][oo] = a0 + bo;
        acc[1][oo] = a1 + bo;
    }

    #pragma unroll
    for (int r = 0; r < K1_R; ++r) {
        float s1 = acc[r][0] + acc[r][1];
        float s2 = acc[r][0] * acc[r][0] + acc[r][1] * acc[r][1];
        #pragma unroll
        for (int off = 32; off > 0; off >>= 1) {
            s1 += __shfl_down(s1, off);
            s2 += __shfl_down(s2, off);
        }
        if (lane == 0) { red[wid][r][0] = s1; red[wid][r][1] = s2; }
    }
    __syncthreads();
    if (t < K1_R) {
        float s1 = red[0][t][0] + red[1][t][0] + red[2][t][0] + red[3][t][0];
        float s2 = red[0][t][1] + red[1][t][1] + red[2][t][1] + red[3][t][1];
        float mu  = s1 / (float)OUT_;
        float var = s2 / (float)OUT_ - mu * mu;
        smu[t] = mu;
        srs[t] = rsqrtf(var + LN_EPS_);
    }
    __syncthreads();

    #pragma unroll
    for (int oo = 0; oo < 2; ++oo) {
        const int o = t + oo * 256;
        const float g  = ln_g[o];
        const float bb = ln_b[o];
        #pragma unroll
        for (int r = 0; r < K1_R; ++r) {
            float z  = (acc[r][oo] - smu[r]) * srs[r] * g + bb;
            float sg = 1.f / (1.f + expf(-z));
            float w  = weights[(size_t)o * IN_ + (i0 + r)];
            wv[(size_t)(i0 + r) * OUT_ + o] = make_float2(w, fabsf(w) * sg);
        }
    }
}

// ---------------------------------------------------------------------------
// K2: split-K partials of
//   dot = sum_i x*W,  s = sum_i u*v,  m = max_i u*v   (u = x*|x|)
// stored as lin = dot - DELTA*s (add-combinable) and m.
// Tile 32b x 16o, chunk 128 i, grid (32, 8, 4) = 1024 blocks (4/CU, 16 w/CU).
// Both operands staged in LDS; inner loop is LDS+VALU only.
// xs rows padded to 33 float4 -> bl-strided b128 reads conflict-free.
// ws rows padded to 17 float2 -> ot reads cover all 32 banks once.
// ---------------------------------------------------------------------------
#define K2_SK 4
#define K2_CH 128           // IN_/K2_SK
#define K2_BO (B_ * OUT_)   // 131072

__global__ __launch_bounds__(256)
void k2_partials(const float* __restrict__ x,
                 const float2* __restrict__ wv,
                 float* __restrict__ plin,
                 float* __restrict__ pmax) {
    __shared__ float4 xs4[32 * 33];     // 16.9 KB
    __shared__ float2 ws2[K2_CH * 17];  // 17.4 KB

    const int t  = threadIdx.x;
    const int ot = t & 15;
    const int bl = t >> 4;
    const int o0 = blockIdx.x * 16;
    const int b0 = blockIdx.y * 32;
    const int sk = blockIdx.z;
    const int i0 = sk * K2_CH;

    // stage x tile (32 rows x 128 cols)
    #pragma unroll
    for (int k = 0; k < 4; ++k) {
        int p    = t + k * 256;
        int row  = p >> 5;
        int col4 = p & 31;
        xs4[row * 33 + col4] = reinterpret_cast<const float4*>(
            x + (size_t)(b0 + row) * IN_ + i0)[col4];
    }
    // stage wv tile (128 rows x 16 cols), 128B-contiguous per 16 lanes
    #pragma unroll
    for (int k = 0; k < 8; ++k) {
        int r = (t >> 4) + 16 * k;
        int c = t & 15;
        ws2[r * 17 + c] = wv[(size_t)(i0 + r) * OUT_ + o0 + c];
    }
    __syncthreads();

    const int o = o0 + ot;
    float da = 0.f, sa = 0.f, ma = -INFINITY;
    float db = 0.f, sb = 0.f, mb = -INFINITY;

    #pragma unroll 4
    for (int i4 = 0; i4 < K2_CH / 4; ++i4) {
        float4 xa = xs4[bl * 33 + i4];
        float4 xb = xs4[(bl + 16) * 33 + i4];
        float4 ua = make_float4(xa.x * fabsf(xa.x), xa.y * fabsf(xa.y),
                                xa.z * fabsf(xa.z), xa.w * fabsf(xa.w));
        float4 ub = make_float4(xb.x * fabsf(xb.x), xb.y * fabsf(xb.y),
                                xb.z * fabsf(xb.z), xb.w * fabsf(xb.w));
        float2 w0 = ws2[(4 * i4 + 0) * 17 + ot];
        float2 w1 = ws2[(4 * i4 + 1) * 17 + ot];
        float2 w2 = ws2[(4 * i4 + 2) * 17 + ot];
        float2 w3 = ws2[(4 * i4 + 3) * 17 + ot];
        float p;
        da = fmaf(xa.x, w0.x, da); p = ua.x * w0.y; sa += p; ma = fmaxf(ma, p);
        db = fmaf(xb.x, w0.x, db); p = ub.x * w0.y; sb += p; mb = fmaxf(mb, p);
        da = fmaf(xa.y, w1.x, da); p = ua.y * w1.y; sa += p; ma = fmaxf(ma, p);
        db = fmaf(xb.y, w1.x, db); p = ub.y * w1.y; sb += p; mb = fmaxf(mb, p);
        da = fmaf(xa.z, w2.x, da); p = ua.z * w2.y; sa += p; ma = fmaxf(ma, p);
        db = fmaf(xb.z, w2.x, db); p = ub.z * w2.y; sb += p; mb = fmaxf(mb, p);
        da = fmaf(xa.w, w3.x, da); p = ua.w * w3.y; sa += p; ma = fmaxf(ma, p);
        db = fmaf(xb.w, w3.x, db); p = ub.w * w3.y; sb += p; mb = fmaxf(mb, p);
    }

    const size_t boa = (size_t)(b0 + bl) * OUT_ + o;
    const size_t bob = boa + (size_t)16 * OUT_;
    plin[(size_t)sk * K2_BO + boa] = da - DELTA_ * sa;
    pmax[(size_t)sk * K2_BO + boa] = ma;
    plin[(size_t)sk * K2_BO + bob] = db - DELTA_ * sb;
    pmax[(size_t)sk * K2_BO + bob] = mb;
}

// ---------------------------------------------------------------------------
// K3: combine split-K partials. out = sum_sk lin + DELTA * max_sk m.
// ---------------------------------------------------------------------------
__global__ __launch_bounds__(256)
void k3_combine(const float* __restrict__ plin,
                const float* __restrict__ pmax,
                float* __restrict__ out) {
    const int g = blockIdx.x * 256 + threadIdx.x;
    float l = plin[g] + plin[K2_BO + g] + plin[2 * K2_BO + g] + plin[3 * K2_BO + g];
    float m = fmaxf(fmaxf(pmax[g], pmax[K2_BO + g]),
                    fmaxf(pmax[2 * K2_BO + g], pmax[3 * K2_BO + g]));
    out[g] = l + DELTA_ * m;
}

// ---------------------------------------------------------------------------
extern "C" void kernel_launch(void* const* d_in, const int* in_sizes, int n_in,
                              void* d_out, int out_size, void* d_ws, size_t ws_size,
                              hipStream_t stream) {
    const float* x        = (const float*)d_in[0];
    const float* weights  = (const float*)d_in[1];
    const float* pred_emb = (const float*)d_in[2];
    const float* attn_w   = (const float*)d_in[3];
    const float* attn_b   = (const float*)d_in[4];
    const float* ln_g     = (const float*)d_in[5];
    const float* ln_b     = (const float*)d_in[6];
    float* out = (float*)d_out;

    // workspace layout: wv (2 MB) | plin (2 MB) | pmax (2 MB)
    float2* wv   = (float2*)d_ws;
    float*  plin = (float*)d_ws + 2 * (size_t)IN_ * OUT_;
    float*  pmax = plin + (size_t)K2_SK * K2_BO;

    k1_scores_ln_sig<<<IN_ / K1_R, 256, 0, stream>>>(
        pred_emb, attn_w, attn_b, ln_g, ln_b, weights, wv);

    k2_partials<<<dim3(OUT_ / 16, B_ / 32, K2_SK), 256, 0, stream>>>(
        x, wv, plin, pmax);

    k3_combine<<<K2_BO / 256, 256, 0, stream>>>(plin, pmax, out);
}

// Round 3
// 99.586 us; speedup vs baseline: 1.6267x; 1.0185x over previous
//
#include <hip/hip_runtime.h>
#include <hip/hip_bf16.h>
#include <math.h>

#define B_   256
#define IN_  512
#define OUT_ 512
#define E_   256
#define DELTA_ 0.1f
#define LN_EPS_ 1e-5f

// ---------------------------------------------------------------------------
// K1: scores[i][o] = pred_emb[i,:]·attn_w[o,:] + attn_b[o]; row-LN over o;
//     sigmoid; wv[i][o] = (W[o][i], |W[o][i]|*sig[i][o]).
// 512 threads (8 waves/CU), 2 i-rows per block, grid 256 (1 block/CU).
// Each thread owns one o for both rows -> attn_w float4 reused 2x in regs.
// ---------------------------------------------------------------------------
__global__ __launch_bounds__(512)
void k1_scores_ln_sig(const float* __restrict__ pred_emb,
                      const float* __restrict__ attn_w,
                      const float* __restrict__ attn_b,
                      const float* __restrict__ ln_g,
                      const float* __restrict__ ln_b,
                      const float* __restrict__ weights,
                      float2* __restrict__ wv) {
    __shared__ float pe[2][E_];        // 2 KB
    __shared__ float red[8][2][2];     // [wave][row][{s1,s2}]
    __shared__ float smu[2], srs[2];

    const int t    = threadIdx.x;      // 0..511
    const int lane = t & 63;
    const int wid  = t >> 6;           // 0..7
    const int i0   = blockIdx.x * 2;
    const int o    = t;

    // stage both pred_emb rows: 512 threads load 512 floats
    pe[t >> 8][t & 255] = pred_emb[(size_t)(i0 + (t >> 8)) * E_ + (t & 255)];
    __syncthreads();

    const float4* p0 = reinterpret_cast<const float4*>(pe[0]);
    const float4* p1 = reinterpret_cast<const float4*>(pe[1]);
    const float4* wrow = reinterpret_cast<const float4*>(attn_w + (size_t)o * E_);

    float a0 = 0.f, a1 = 0.f;
    #pragma unroll 8
    for (int e4 = 0; e4 < E_ / 4; ++e4) {
        float4 w4 = wrow[e4];
        float4 q0 = p0[e4];
        float4 q1 = p1[e4];
        a0 += q0.x * w4.x + q0.y * w4.y + q0.z * w4.z + q0.w * w4.w;
        a1 += q1.x * w4.x + q1.y * w4.y + q1.z * w4.z + q1.w * w4.w;
    }
    const float bo = attn_b[o];
    a0 += bo;
    a1 += bo;

    // LN stats per row over 512 o-values (one per thread)
    {
        float s1 = a0, s2 = a0 * a0;
        float u1 = a1, u2 = a1 * a1;
        #pragma unroll
        for (int off = 32; off > 0; off >>= 1) {
            s1 += __shfl_down(s1, off);
            s2 += __shfl_down(s2, off);
            u1 += __shfl_down(u1, off);
            u2 += __shfl_down(u2, off);
        }
        if (lane == 0) {
            red[wid][0][0] = s1; red[wid][0][1] = s2;
            red[wid][1][0] = u1; red[wid][1][1] = u2;
        }
    }
    __syncthreads();
    if (t < 2) {
        float s1 = 0.f, s2 = 0.f;
        #pragma unroll
        for (int w = 0; w < 8; ++w) { s1 += red[w][t][0]; s2 += red[w][t][1]; }
        float mu  = s1 / (float)OUT_;
        float var = s2 / (float)OUT_ - mu * mu;
        smu[t] = mu;
        srs[t] = rsqrtf(var + LN_EPS_);
    }
    __syncthreads();

    const float g  = ln_g[o];
    const float bb = ln_b[o];
    float z0 = (a0 - smu[0]) * srs[0] * g + bb;
    float z1 = (a1 - smu[1]) * srs[1] * g + bb;
    float sg0 = 1.f / (1.f + expf(-z0));
    float sg1 = 1.f / (1.f + expf(-z1));

    // adjacent i -> one float2 load of weights[o][i0..i0+1]
    float2 w01 = *reinterpret_cast<const float2*>(weights + (size_t)o * IN_ + i0);
    wv[(size_t)(i0 + 0) * OUT_ + o] = make_float2(w01.x, fabsf(w01.x) * sg0);
    wv[(size_t)(i0 + 1) * OUT_ + o] = make_float2(w01.y, fabsf(w01.y) * sg1);
}

// ---------------------------------------------------------------------------
// K2: split-K partials of dot = sum_i x*W, s = sum_i u*v, m = max_i u*v
//     (u = x*|x|), stored as lin = dot - DELTA*s and m.
// Tile: 64 b x 16 o; 256 thr = 16 o-lanes x 16 b-lanes, each b-lane owns
// 4 b-rows (bl, +16, +32, +48). Chunk 128 i, SK=4 -> grid (32,4,4)=512
// blocks, 2 blocks/CU (LDS 51 KB). Inner loop LDS+VALU only.
// xs rows padded to 33 float4 (b-lane reads land on distinct banks);
// ws rows padded to 17 float2 (16 o-lanes cover all 32 banks).
// ---------------------------------------------------------------------------
#define K2_SK 4
#define K2_CH 128
#define K2_BO (B_ * OUT_)   // 131072

__global__ __launch_bounds__(256)
void k2_partials(const float* __restrict__ x,
                 const float2* __restrict__ wv,
                 float* __restrict__ plin,
                 float* __restrict__ pmax) {
    __shared__ float4 xs4[64 * 33];     // 33.8 KB
    __shared__ float2 ws2[K2_CH * 17];  // 17.4 KB

    const int t  = threadIdx.x;
    const int ot = t & 15;
    const int bl = t >> 4;              // 0..15
    const int o0 = blockIdx.x * 16;
    const int b0 = blockIdx.y * 64;
    const int sk = blockIdx.z;
    const int i0 = sk * K2_CH;

    // stage x tile (64 rows x 128 cols)
    #pragma unroll
    for (int k = 0; k < 8; ++k) {
        int p    = t + k * 256;         // 0..2047
        int row  = p >> 5;
        int col4 = p & 31;
        xs4[row * 33 + col4] = reinterpret_cast<const float4*>(
            x + (size_t)(b0 + row) * IN_ + i0)[col4];
    }
    // stage wv tile (128 rows x 16 cols)
    #pragma unroll
    for (int k = 0; k < 8; ++k) {
        int r = bl + 16 * k;
        ws2[r * 17 + ot] = wv[(size_t)(i0 + r) * OUT_ + o0 + ot];
    }
    __syncthreads();

    const int o = o0 + ot;
    float d0 = 0.f, s0 = 0.f, m0 = -INFINITY;
    float d1 = 0.f, s1 = 0.f, m1 = -INFINITY;
    float d2 = 0.f, s2 = 0.f, m2 = -INFINITY;
    float d3 = 0.f, s3 = 0.f, m3 = -INFINITY;

    #pragma unroll 2
    for (int i4 = 0; i4 < K2_CH / 4; ++i4) {
        float4 x0 = xs4[(bl +  0) * 33 + i4];
        float4 x1 = xs4[(bl + 16) * 33 + i4];
        float4 x2 = xs4[(bl + 32) * 33 + i4];
        float4 x3 = xs4[(bl + 48) * 33 + i4];
        float2 w0 = ws2[(4 * i4 + 0) * 17 + ot];
        float2 w1 = ws2[(4 * i4 + 1) * 17 + ot];
        float2 w2 = ws2[(4 * i4 + 2) * 17 + ot];
        float2 w3 = ws2[(4 * i4 + 3) * 17 + ot];
        float p;
        float4 u0 = make_float4(x0.x * fabsf(x0.x), x0.y * fabsf(x0.y),
                                x0.z * fabsf(x0.z), x0.w * fabsf(x0.w));
        float4 u1 = make_float4(x1.x * fabsf(x1.x), x1.y * fabsf(x1.y),
                                x1.z * fabsf(x1.z), x1.w * fabsf(x1.w));
        float4 u2 = make_float4(x2.x * fabsf(x2.x), x2.y * fabsf(x2.y),
                                x2.z * fabsf(x2.z), x2.w * fabsf(x2.w));
        float4 u3 = make_float4(x3.x * fabsf(x3.x), x3.y * fabsf(x3.y),
                                x3.z * fabsf(x3.z), x3.w * fabsf(x3.w));

        d0 = fmaf(x0.x, w0.x, d0); p = u0.x * w0.y; s0 += p; m0 = fmaxf(m0, p);
        d1 = fmaf(x1.x, w0.x, d1); p = u1.x * w0.y; s1 += p; m1 = fmaxf(m1, p);
        d2 = fmaf(x2.x, w0.x, d2); p = u2.x * w0.y; s2 += p; m2 = fmaxf(m2, p);
        d3 = fmaf(x3.x, w0.x, d3); p = u3.x * w0.y; s3 += p; m3 = fmaxf(m3, p);

        d0 = fmaf(x0.y, w1.x, d0); p = u0.y * w1.y; s0 += p; m0 = fmaxf(m0, p);
        d1 = fmaf(x1.y, w1.x, d1); p = u1.y * w1.y; s1 += p; m1 = fmaxf(m1, p);
        d2 = fmaf(x2.y, w1.x, d2); p = u2.y * w1.y; s2 += p; m2 = fmaxf(m2, p);
        d3 = fmaf(x3.y, w1.x, d3); p = u3.y * w1.y; s3 += p; m3 = fmaxf(m3, p);

        d0 = fmaf(x0.z, w2.x, d0); p = u0.z * w2.y; s0 += p; m0 = fmaxf(m0, p);
        d1 = fmaf(x1.z, w2.x, d1); p = u1.z * w2.y; s1 += p; m1 = fmaxf(m1, p);
        d2 = fmaf(x2.z, w2.x, d2); p = u2.z * w2.y; s2 += p; m2 = fmaxf(m2, p);
        d3 = fmaf(x3.z, w2.x, d3); p = u3.z * w2.y; s3 += p; m3 = fmaxf(m3, p);

        d0 = fmaf(x0.w, w3.x, d0); p = u0.w * w3.y; s0 += p; m0 = fmaxf(m0, p);
        d1 = fmaf(x1.w, w3.x, d1); p = u1.w * w3.y; s1 += p; m1 = fmaxf(m1, p);
        d2 = fmaf(x2.w, w3.x, d2); p = u2.w * w3.y; s2 += p; m2 = fmaxf(m2, p);
        d3 = fmaf(x3.w, w3.x, d3); p = u3.w * w3.y; s3 += p; m3 = fmaxf(m3, p);
    }

    const size_t base = (size_t)sk * K2_BO + (size_t)b0 * OUT_ + o;
    plin[base + (size_t)(bl +  0) * OUT_] = d0 - DELTA_ * s0;
    plin[base + (size_t)(bl + 16) * OUT_] = d1 - DELTA_ * s1;
    plin[base + (size_t)(bl + 32) * OUT_] = d2 - DELTA_ * s2;
    plin[base + (size_t)(bl + 48) * OUT_] = d3 - DELTA_ * s3;
    pmax[base + (size_t)(bl +  0) * OUT_] = m0;
    pmax[base + (size_t)(bl + 16) * OUT_] = m1;
    pmax[base + (size_t)(bl + 32) * OUT_] = m2;
    pmax[base + (size_t)(bl + 48) * OUT_] = m3;
}

// ---------------------------------------------------------------------------
// K3: combine split-K partials, float4-wide. out = sum lin + DELTA * max m.
// ---------------------------------------------------------------------------
__global__ __launch_bounds__(256)
void k3_combine(const float4* __restrict__ plin4,
                const float4* __restrict__ pmax4,
                float4* __restrict__ out4) {
    const int g = blockIdx.x * 256 + threadIdx.x;   // 0..32767
    const int Q = K2_BO / 4;                        // 32768
    float4 l0 = plin4[g], l1 = plin4[Q + g], l2 = plin4[2 * Q + g], l3 = plin4[3 * Q + g];
    float4 m0 = pmax4[g], m1 = pmax4[Q + g], m2 = pmax4[2 * Q + g], m3 = pmax4[3 * Q + g];
    float4 r;
    r.x = (l0.x + l1.x + l2.x + l3.x) + DELTA_ * fmaxf(fmaxf(m0.x, m1.x), fmaxf(m2.x, m3.x));
    r.y = (l0.y + l1.y + l2.y + l3.y) + DELTA_ * fmaxf(fmaxf(m0.y, m1.y), fmaxf(m2.y, m3.y));
    r.z = (l0.z + l1.z + l2.z + l3.z) + DELTA_ * fmaxf(fmaxf(m0.z, m1.z), fmaxf(m2.z, m3.z));
    r.w = (l0.w + l1.w + l2.w + l3.w) + DELTA_ * fmaxf(fmaxf(m0.w, m1.w), fmaxf(m2.w, m3.w));
    out4[g] = r;
}

// ---------------------------------------------------------------------------
extern "C" void kernel_launch(void* const* d_in, const int* in_sizes, int n_in,
                              void* d_out, int out_size, void* d_ws, size_t ws_size,
                              hipStream_t stream) {
    const float* x        = (const float*)d_in[0];
    const float* weights  = (const float*)d_in[1];
    const float* pred_emb = (const float*)d_in[2];
    const float* attn_w   = (const float*)d_in[3];
    const float* attn_b   = (const float*)d_in[4];
    const float* ln_g     = (const float*)d_in[5];
    const float* ln_b     = (const float*)d_in[6];

    // workspace layout: wv (2 MB) | plin (2 MB) | pmax (2 MB)
    float2* wv   = (float2*)d_ws;
    float*  plin = (float*)d_ws + 2 * (size_t)IN_ * OUT_;
    float*  pmax = plin + (size_t)K2_SK * K2_BO;

    k1_scores_ln_sig<<<IN_ / 2, 512, 0, stream>>>(
        pred_emb, attn_w, attn_b, ln_g, ln_b, weights, wv);

    k2_partials<<<dim3(OUT_ / 16, B_ / 64, K2_SK), 256, 0, stream>>>(
        x, wv, plin, pmax);

    k3_combine<<<K2_BO / 4 / 256, 256, 0, stream>>>(
        (const float4*)plin, (const float4*)pmax, (float4*)d_out);
}